// Round 13
// baseline (381.271 us; speedup 1.0000x reference)
//
#include <hip/hip_runtime.h>
#include <cfloat>
#include <cmath>

#define B_ 64
#define N_ 8192
#define D_ 128
#define M_ 64
#define CROWS 64              // rows per chunk (32 KB fp32 LDS tile)
#define NCHUNK 4              // chunks per block
#define BROWS (CROWS*NCHUNK)  // 256 rows per block
#define NBLK (N_/BROWS)       // 32 blocks per batch
#define ALPHA_ 0.1f
#define EPS_ 1e-10f

typedef __attribute__((ext_vector_type(4))) float f32x4;
typedef __attribute__((ext_vector_type(8))) short bf16x8;

// global_load_lds: LDS dest is wave-uniform base + lane*16 (m104); the
// per-lane GLOBAL address carries the inverse swizzle (rule #21).
#define GLOAD_LDS16(gp, lp) __builtin_amdgcn_global_load_lds(              \
    (const __attribute__((address_space(1))) void*)(gp),                   \
    (__attribute__((address_space(3))) void*)(lp), 16, 0, 0)

// Kernel 1: per (b, 256-row block): xp = x . pv^T via bf16 trunc-split MFMA
// (3 products), fused min over n of (x2[n] - 2*xp).  p2[m] in kernel 2.
// fp32 x streamed global->LDS via 2-deep ring (no reg staging, no stage
// phase); split to bf16 hi/lo at LDS->reg time; x2 via in-compute shuffles.
// LDS slot swizzle: LDS[row][slot] holds x[row][slot ^ (row&7)] (16B slots).
__global__ __launch_bounds__(256, 2)
void protomin_mfma(const float* __restrict__ x, const float* __restrict__ pv,
                   float* __restrict__ wsv, int* __restrict__ wsa) {
    __shared__ float ring[2][CROWS * D_];    // 2 x 32 KB fp32 ring
    __shared__ float redv[2][M_];
    __shared__ int   redp[2][M_];

    const int tid = threadIdx.x;
    const int w   = tid >> 6;                // wave 0..3
    const int l   = tid & 63;                // lane
    const int lm  = l & 15, lg = l >> 4;
    const int wr  = w & 1;                   // row-half of chunk
    const int wm  = w >> 1;                  // col-half of protos
    const int bid = blockIdx.x;
    const int b   = bid >> 5;                // NBLK = 32
    const int nbase = (bid & 31) * BROWS;

    const float* xblk = x + ((size_t)b * N_ + nbase) * D_;

    // ---- issue a chunk's 8 global_load_lds (per wave) ----
    // inst i: segment s=w*8+i -> LDS bytes [s*1024, s*1024+1024) = rows 2s,2s+1
    // lane l -> row 2s+(l>>5), LDS slot j=l&31; global source slot j^(row&7)
    auto issue = [&](int buf, int c) {
#pragma unroll
        for (int i = 0; i < 8; ++i) {
            int s    = w * 8 + i;
            int row  = 2 * s + (l >> 5);
            int gsl  = (l & 31) ^ (row & 7);
            const float* gp = xblk + (size_t)c * CROWS * D_ + row * D_ + gsl * 4;
            GLOAD_LDS16(gp, &ring[buf][s * 256]);
        }
    };

    // ---- B fragments: pv trunc-split to bf16 hi/lo, in registers ----
    // B-frag layout (16x16x32): col m = lane&15, k = (lane>>4)*8 + j
    bf16x8 Bh[2][4], Bl[2][4];               // [mtile][ktile] = 64 VGPR
#pragma unroll
    for (int mti = 0; mti < 2; ++mti) {
#pragma unroll
        for (int kt = 0; kt < 4; ++kt) {
            const float* p = pv + (wm * 32 + mti * 16 + lm) * D_ + kt * 32 + lg * 8;
#pragma unroll
            for (int h = 0; h < 2; ++h) {
                f32x4 pq = *(const f32x4*)(p + 4 * h);
#pragma unroll
                for (int j = 0; j < 4; ++j) {
                    unsigned u = __float_as_uint(pq[j]);
                    float hf = __uint_as_float(u & 0xffff0000u);
                    Bh[mti][kt][4 * h + j] = (short)(u >> 16);
                    float rem = pq[j] - hf;
                    Bl[mti][kt][4 * h + j] = (short)(__float_as_uint(rem) >> 16);
                }
            }
        }
    }

    float bv[2]; int bp[2];
#pragma unroll
    for (int mti = 0; mti < 2; ++mti) { bv[mti] = FLT_MAX; bp[mti] = 0; }

    // prologue: fill ring 2 deep; barrier's implicit vmcnt drain makes both
    // chunks visible (one-time ~latency cost per block)
    issue(0, 0);
    issue(1, 1);
    __syncthreads();

#pragma unroll
    for (int c = 0; c < NCHUNK; ++c) {
        const int buf = c & 1;
        f32x4 acc[2][2] = {};                // [rt][mti]; C: col=lm, row=lg*4+q
        float x2p[2] = {0.f, 0.f};           // per-lane partial of row wr*32+rt*16+lm

#pragma unroll
        for (int kt = 0; kt < 4; ++kt) {
            bf16x8 ah[2], al[2];
#pragma unroll
            for (int rt = 0; rt < 2; ++rt) {
                const int row = wr * 32 + rt * 16 + lm;
                const int rs  = row & 7;
                const int j0  = kt * 8 + lg * 2;
                const float* base = &ring[buf][row * D_];
                f32x4 v0 = *(const f32x4*)(base + (((j0    ) ^ rs) << 2));
                f32x4 v1 = *(const f32x4*)(base + (((j0 + 1) ^ rs) << 2));
                // x2 partial (fp32, exact path reused from split)
                x2p[rt] = fmaf(v0[0], v0[0], x2p[rt]);
                x2p[rt] = fmaf(v0[1], v0[1], x2p[rt]);
                x2p[rt] = fmaf(v0[2], v0[2], x2p[rt]);
                x2p[rt] = fmaf(v0[3], v0[3], x2p[rt]);
                x2p[rt] = fmaf(v1[0], v1[0], x2p[rt]);
                x2p[rt] = fmaf(v1[1], v1[1], x2p[rt]);
                x2p[rt] = fmaf(v1[2], v1[2], x2p[rt]);
                x2p[rt] = fmaf(v1[3], v1[3], x2p[rt]);
                // trunc split + pack: AH.u[p] = elems 2p,2p+1 (lo short = even elem)
                union { bf16x8 v; unsigned u[4]; } AH, AL;
#pragma unroll
                for (int pq = 0; pq < 2; ++pq) {
                    f32x4 vv = pq ? v1 : v0;
#pragma unroll
                    for (int e = 0; e < 2; ++e) {
                        unsigned u0 = __float_as_uint(vv[2 * e]);
                        unsigned u1 = __float_as_uint(vv[2 * e + 1]);
                        unsigned h0 = u0 & 0xffff0000u, h1 = u1 & 0xffff0000u;
                        AH.u[pq * 2 + e] = (u0 >> 16) | h1;
                        float r0 = vv[2 * e]     - __uint_as_float(h0);
                        float r1 = vv[2 * e + 1] - __uint_as_float(h1);
                        AL.u[pq * 2 + e] = (__float_as_uint(r0) >> 16) |
                                           (__float_as_uint(r1) & 0xffff0000u);
                    }
                }
                ah[rt] = AH.v; al[rt] = AL.v;
            }
#pragma unroll
            for (int rt = 0; rt < 2; ++rt) {
#pragma unroll
                for (int mti = 0; mti < 2; ++mti) {
                    acc[rt][mti] = __builtin_amdgcn_mfma_f32_16x16x32_bf16(ah[rt], Bh[mti][kt], acc[rt][mti], 0, 0, 0);
                    acc[rt][mti] = __builtin_amdgcn_mfma_f32_16x16x32_bf16(al[rt], Bh[mti][kt], acc[rt][mti], 0, 0, 0);
                    acc[rt][mti] = __builtin_amdgcn_mfma_f32_16x16x32_bf16(ah[rt], Bl[mti][kt], acc[rt][mti], 0, 0, 0);
                }
            }
        }

        // x2 finish: butterfly over lg (lane bits 4,5) -> lane lm holds full
        // x2 of row wr*32+rt*16+lm; then gather per fold-row via shfl
#pragma unroll
        for (int rt = 0; rt < 2; ++rt) {
            x2p[rt] += __shfl_xor(x2p[rt], 16);
            x2p[rt] += __shfl_xor(x2p[rt], 32);
        }

        // fold: cand = x2[n] - 2*xp ; q ascending keeps n ascending for ties
#pragma unroll
        for (int rt = 0; rt < 2; ++rt) {
            const int rbase = wr * 32 + rt * 16 + lg * 4;
            const int npos0 = nbase + c * CROWS + rbase;
#pragma unroll
            for (int q = 0; q < 4; ++q) {
                float x2r = __shfl(x2p[rt], lg * 4 + q);   // from lane lm'=lg*4+q
#pragma unroll
                for (int mti = 0; mti < 2; ++mti) {
                    float cand = fmaf(-2.f, acc[rt][mti][q], x2r);
                    if (cand < bv[mti]) { bv[mti] = cand; bp[mti] = npos0 + q; }
                }
            }
        }

        if (c + 1 < NCHUNK) {
            __syncthreads();                 // all reads of ring[buf] done;
                                             // implicit drain hits chunk-old
                                             // loads only (cheap)
            if (c + 2 < NCHUNK) issue(buf, c + 2);   // refill freed buffer
        }
    }

    // cross-lane reduce over lg (rows within 16-tile), tie -> smaller n
#pragma unroll
    for (int mti = 0; mti < 2; ++mti) {
        float v = bv[mti]; int p = bp[mti];
#pragma unroll
        for (int off = 16; off <= 32; off <<= 1) {
            float ov = __shfl_xor(v, off);
            int   op = __shfl_xor(p, off);
            if (ov < v || (ov == v && op < p)) { v = ov; p = op; }
        }
        if (l < 16) { redv[wr][wm * 32 + mti * 16 + l] = v;
                      redp[wr][wm * 32 + mti * 16 + l] = p; }
    }
    __syncthreads();

    // cross-wave (row-half) reduce; one entry per (b, block, m)
    if (tid < M_) {
        float v = redv[0][tid]; int p = redp[0][tid];
        float ov = redv[1][tid]; int op = redp[1][tid];
        if (ov < v || (ov == v && op < p)) { v = ov; p = op; }
        wsv[(size_t)bid * M_ + tid] = v;
        wsa[(size_t)bid * M_ + tid] = p;
    }
}

// Kernel 2: add p2[m], reduce blocks, sqrt/exp, per-batch argmin over m.
__global__ void finalize_kernel(const float* __restrict__ wsv,
                                const int* __restrict__ wsa,
                                const float* __restrict__ pv,
                                float* __restrict__ out) {
    const int b = blockIdx.x;
    const int m = threadIdx.x;

    float p2 = 0.f;
    const f32x4* pp = (const f32x4*)(pv + m * D_);
#pragma unroll 8
    for (int j = 0; j < 32; ++j) {
        f32x4 v = pp[j];
        p2 = fmaf(v[0], v[0], p2); p2 = fmaf(v[1], v[1], p2);
        p2 = fmaf(v[2], v[2], p2); p2 = fmaf(v[3], v[3], p2);
    }

    float v = FLT_MAX; int p = 0;
    for (int bc = 0; bc < NBLK; ++bc) {      // ascending n
        size_t idx = ((size_t)(b * NBLK + bc)) * M_ + m;
        float nv2 = wsv[idx]; int np = wsa[idx];
        if (nv2 < v || (nv2 == v && np < p)) { v = nv2; p = np; }
    }
    float dist = sqrtf(fmaxf(v + p2, 0.f));
    out[b * M_ + m] = expf(EPS_ - ALPHA_ * dist);

    __shared__ float sv[M_];
    __shared__ int   sa[M_];
    sv[m] = dist; sa[m] = p;
    __syncthreads();
    if (m == 0) {
        float best = FLT_MAX; int bpos = 0;
        for (int k = 0; k < M_; ++k)         // ascending m, strict < = first-min
            if (sv[k] < best) { best = sv[k]; bpos = sa[k]; }
        out[B_ * M_ + b] = (float)bpos;
    }
}

extern "C" void kernel_launch(void* const* d_in, const int* in_sizes, int n_in,
                              void* d_out, int out_size, void* d_ws, size_t ws_size,
                              hipStream_t stream) {
    const float* x  = (const float*)d_in[0];
    const float* pv = (const float*)d_in[1];
    float* out = (float*)d_out;

    float* wsv = (float*)d_ws;
    int*   wsa = (int*)((char*)d_ws + (size_t)B_ * NBLK * M_ * sizeof(float));

    hipLaunchKernelGGL(protomin_mfma, dim3(B_ * NBLK), dim3(256), 0, stream,
                       x, pv, wsv, wsa);
    hipLaunchKernelGGL(finalize_kernel, dim3(B_), dim3(M_), 0, stream,
                       wsv, wsa, pv, out);
}